// Round 6
// baseline (170.914 us; speedup 1.0000x reference)
//
#include <hip/hip_runtime.h>
#include <hip/hip_bf16.h>

// Variable_Attention: out = softmax(relu((x@WQ)(x@WK)^T)/sqrt(128), axis=-1)
// B=16, N=2048, T=96, D=128. fp32 in/out.
//
// QK^T/sqrt(d) = x Ms x^T with Ms = (WQ WK^T)/sqrt(d) (96x96, exact fp32):
//   k_m    : Ms^T -> fp16 hi/lo split (mth/mtl)
//   k_fuse : reads x once (LDS-staged); emits y = x@Ms (fp32, pre-scaled)
//            and Bp = x split fp16 hi/lo in MFMA B-fragment stream order
//            Bp[gct(2048)][ks(3)][hl(2)][lane(64)][8] (1KB bursts per frag)
//   k_attn : S = y@x^T (K=96, 3-term split-fp16 MFMA) fused relu/softmax.
//            BM=16 rows/block, 1024 thr (16 waves), wave owns 128 cols
//            (8 col-tiles): acc=32 VGPR -> 4 waves/SIMD (16 waves/CU).
//            Depth-2 register ping-pong B prefetch; 4 co-resident waves
//            hide L2 latency; no LDS in main loop; NT loads/stores.
// Workspace: ~38 MB.

typedef _Float16 f16;
typedef _Float16 half8 __attribute__((ext_vector_type(8)));
typedef float float4v __attribute__((ext_vector_type(4)));

#define B_ 16
#define N_ 2048
#define T_ 96
#define D_ 128

// ---------------------------------------------------------------------------
// k_m: Ms[t][t2] = (sum_d WQ[t,d]*WK[t2,d])/sqrt(128), transposed + split.
// ---------------------------------------------------------------------------
__global__ void k_m(const float* __restrict__ WQ, const float* __restrict__ WK,
                    f16* __restrict__ mth, f16* __restrict__ mtl) {
    int i = blockIdx.x * 256 + threadIdx.x;
    if (i >= T_ * T_) return;
    int t = i / T_, t2 = i % T_;
    const float4v* q = (const float4v*)(WQ + (size_t)t * D_);
    const float4v* k = (const float4v*)(WK + (size_t)t2 * D_);
    float s = 0.0f;
#pragma unroll
    for (int d = 0; d < D_ / 4; ++d) {
        float4v a = q[d], b = k[d];
        s += a[0] * b[0] + a[1] * b[1] + a[2] * b[2] + a[3] * b[3];
    }
    s *= 0.088388347648318447f;   // 1/sqrt(128) folded in (exact fp32 here)
    f16 h = (f16)s;
    mth[t2 * T_ + t] = h;
    mtl[t2 * T_ + t] = (f16)(s - (float)h);
}

// ---------------------------------------------------------------------------
// k_fuse: per block, 128 x-rows staged in LDS (fp32, padded to 100 floats);
// (a) y = x@Ms via split-fp16 MFMA (wave owns 32 rows), (b) Bp pack
// (wave owns 2 col-tiles): frag[gct][ks][hl] = 1KB contiguous.
// ---------------------------------------------------------------------------
__global__ __launch_bounds__(256) void k_fuse(
        const float* __restrict__ x,
        const f16* __restrict__ mth, const f16* __restrict__ mtl,
        float* __restrict__ y, f16* __restrict__ bp) {
    __shared__ float xs[128][100];   // 51.2 KB, +4 pad -> conflict-free reads

    const int tid  = (int)threadIdx.x;
    const int lane = tid & 63;
    const int wave = tid >> 6;
    const int lr = lane & 15;
    const int lk = lane >> 4;
    const size_t rbase = (size_t)blockIdx.x * 128;

    // ---- fill LDS: 128 rows x 96 floats, fully coalesced float4 ----
    const float4v* xg = (const float4v*)(x + rbase * T_);
#pragma unroll
    for (int i = 0; i < 12; ++i) {
        int j = i * 256 + tid;           // 3072 float4 chunks
        int row = j / 24, c4 = j % 24;
        float4v v = xg[j];
        *(float4v*)&xs[row][c4 * 4] = v;
    }
    __syncthreads();

    // ---- y-GEMM: wave owns rows [wave*32, +32) ----
    half8 aH[2][3], aL[2][3];
#pragma unroll
    for (int mt = 0; mt < 2; ++mt)
#pragma unroll
        for (int ks = 0; ks < 3; ++ks) {
            const float* p = &xs[wave * 32 + mt * 16 + lr][ks * 32 + lk * 8];
            float4v v0 = *(const float4v*)p;
            float4v v1 = *(const float4v*)(p + 4);
            half8 h, l;
#pragma unroll
            for (int j = 0; j < 4; ++j) {
                f16 h0 = (f16)v0[j]; h[j] = h0; l[j] = (f16)(v0[j] - (float)h0);
                f16 h1 = (f16)v1[j]; h[4 + j] = h1; l[4 + j] = (f16)(v1[j] - (float)h1);
            }
            aH[mt][ks] = h;
            aL[mt][ks] = l;
        }

    float4v acc[2][6];
#pragma unroll
    for (int mt = 0; mt < 2; ++mt)
#pragma unroll
        for (int nt = 0; nt < 6; ++nt) {
            float4v z = {0.f, 0.f, 0.f, 0.f};
            acc[mt][nt] = z;
        }

#pragma unroll
    for (int nt = 0; nt < 6; ++nt) {
        half8 bH[3], bL[3];
#pragma unroll
        for (int ks = 0; ks < 3; ++ks) {
            size_t off = (size_t)(nt * 16 + lr) * T_ + ks * 32 + lk * 8;
            bH[ks] = *(const half8*)(mth + off);
            bL[ks] = *(const half8*)(mtl + off);
        }
#pragma unroll
        for (int ks = 0; ks < 3; ++ks)
#pragma unroll
            for (int mt = 0; mt < 2; ++mt) {
                acc[mt][nt] = __builtin_amdgcn_mfma_f32_16x16x32_f16(aH[mt][ks], bH[ks], acc[mt][nt], 0, 0, 0);
                acc[mt][nt] = __builtin_amdgcn_mfma_f32_16x16x32_f16(aH[mt][ks], bL[ks], acc[mt][nt], 0, 0, 0);
                acc[mt][nt] = __builtin_amdgcn_mfma_f32_16x16x32_f16(aL[mt][ks], bH[ks], acc[mt][nt], 0, 0, 0);
            }
    }

#pragma unroll
    for (int mt = 0; mt < 2; ++mt)
#pragma unroll
        for (int nt = 0; nt < 6; ++nt)
#pragma unroll
            for (int r = 0; r < 4; ++r)
                y[(rbase + wave * 32 + mt * 16 + lk * 4 + r) * T_ + nt * 16 + lr] = acc[mt][nt][r];

    // ---- Bp pack: wave owns col-tiles wave*2 + {0,1} of this block ----
#pragma unroll
    for (int ctl = 0; ctl < 2; ++ctl) {
        const int lct = wave * 2 + ctl;                 // 0..7
        const size_t gct = rbase / 16 + lct;            // global col-tile
#pragma unroll
        for (int ks = 0; ks < 3; ++ks) {
            const float* p = &xs[lct * 16 + lr][ks * 32 + lk * 8];
            float4v v0 = *(const float4v*)p;
            float4v v1 = *(const float4v*)(p + 4);
            half8 h, l;
#pragma unroll
            for (int j = 0; j < 4; ++j) {
                f16 h0 = (f16)v0[j]; h[j] = h0; l[j] = (f16)(v0[j] - (float)h0);
                f16 h1 = (f16)v1[j]; h[4 + j] = h1; l[4 + j] = (f16)(v1[j] - (float)h1);
            }
            f16* ob = bp + ((gct * 3 + ks) * 2) * 512 + (size_t)lane * 8;
            *(half8*)ob = h;
            *(half8*)(ob + 512) = l;
        }
    }
}

// ---------------------------------------------------------------------------
// k_attn: S = y @ x^T fused relu/softmax. 16 rows x 2048 cols per block,
// 1024 threads (16 waves), wave owns 128 cols = 8 col-tiles.
// acc[8]=32 VGPR; depth-2 register ping-pong B prefetch; 4 waves/SIMD.
// ---------------------------------------------------------------------------
__global__ __launch_bounds__(1024, 4) void k_attn(
        const f16* __restrict__ bp, const float* __restrict__ y,
        float* __restrict__ out) {
    __shared__ float red[16][16];
    __shared__ float stat[16];

    const int tid  = (int)threadIdx.x;
    const int lane = tid & 63;
    const int wave = tid >> 6;
    const int lr = lane & 15;
    const int lk = lane >> 4;

    // XCD-aware bijective swizzle (2048 blocks): contiguous logical range per
    // XCD -> 2 batches' Bp (1.6MB) resident in its L2.
    const int lb   = ((int)blockIdx.x & 7) * 256 + ((int)blockIdx.x >> 3);
    const int b    = lb >> 7;                  // batch
    const int row0 = (lb & 127) << 4;          // 16 rows per block
    const size_t obase = (size_t)b * N_ * N_;

    // ---- A: y rows (fp32, pre-scaled) split on the fly; read-once -> NT ----
    half8 aH[3], aL[3];
#pragma unroll
    for (int ks = 0; ks < 3; ++ks) {
        const float* p = y + ((size_t)b * N_ + row0 + lr) * T_ + ks * 32 + lk * 8;
        float4v v0 = __builtin_nontemporal_load((const float4v*)p);
        float4v v1 = __builtin_nontemporal_load((const float4v*)p + 1);
        half8 h, l;
#pragma unroll
        for (int j = 0; j < 4; ++j) {
            f16 h0 = (f16)v0[j]; h[j] = h0; l[j] = (f16)(v0[j] - (float)h0);
            f16 h1 = (f16)v1[j]; h[4 + j] = h1; l[4 + j] = (f16)(v1[j] - (float)h1);
        }
        aH[ks] = h;
        aL[ks] = l;
    }

    float4v acc[8];
#pragma unroll
    for (int c = 0; c < 8; ++c) {
        float4v z = {0.f, 0.f, 0.f, 0.f};
        acc[c] = z;
    }

    // per-lane global source base for this wave's 8 col-tiles
    const f16* gb = bp + (((size_t)b * 128 + wave * 8) * 6) * 512 + (size_t)lane * 8;

    half8 Bf[2][6];
#pragma unroll
    for (int f = 0; f < 6; ++f) {
        Bf[0][f] = *(const half8*)(gb + f * 512);
        Bf[1][f] = *(const half8*)(gb + 3072 + f * 512);
    }

#pragma unroll
    for (int c = 0; c < 8; ++c) {
        const int cur = c & 1;
#pragma unroll
        for (int ks = 0; ks < 3; ++ks) {
            acc[c] = __builtin_amdgcn_mfma_f32_16x16x32_f16(aH[ks], Bf[cur][ks * 2], acc[c], 0, 0, 0);
            acc[c] = __builtin_amdgcn_mfma_f32_16x16x32_f16(aH[ks], Bf[cur][ks * 2 + 1], acc[c], 0, 0, 0);
            acc[c] = __builtin_amdgcn_mfma_f32_16x16x32_f16(aL[ks], Bf[cur][ks * 2], acc[c], 0, 0, 0);
        }
        if (c + 2 < 8) {
            const f16* nb = gb + (size_t)(c + 2) * 3072;
#pragma unroll
            for (int f = 0; f < 6; ++f)
                Bf[cur][f] = *(const half8*)(nb + f * 512);
        }
    }

    // ---- relu (scale folded into Ms), row max (rows lk*4+r) ----
    float rmax[4];
#pragma unroll
    for (int r = 0; r < 4; ++r) rmax[r] = 0.0f;
#pragma unroll
    for (int c = 0; c < 8; ++c)
#pragma unroll
        for (int r = 0; r < 4; ++r) {
            float v = fmaxf(acc[c][r], 0.0f);
            acc[c][r] = v;
            rmax[r] = fmaxf(rmax[r], v);
        }
#pragma unroll
    for (int r = 0; r < 4; ++r) {
        float m = rmax[r];
        m = fmaxf(m, __shfl_xor(m, 1));
        m = fmaxf(m, __shfl_xor(m, 2));
        m = fmaxf(m, __shfl_xor(m, 4));
        m = fmaxf(m, __shfl_xor(m, 8));
        rmax[r] = m;
    }
    if (lr == 0) {
#pragma unroll
        for (int r = 0; r < 4; ++r)
            red[wave][lk * 4 + r] = rmax[r];
    }
    __syncthreads();
    if (tid < 16) {
        float m = red[0][tid];
#pragma unroll
        for (int w = 1; w < 16; ++w) m = fmaxf(m, red[w][tid]);
        stat[tid] = m;
    }
    __syncthreads();

    float rowm[4], rsum[4];
#pragma unroll
    for (int r = 0; r < 4; ++r) {
        rowm[r] = stat[lk * 4 + r];
        rsum[r] = 0.0f;
    }

    // ---- exp, row sum ----
#pragma unroll
    for (int c = 0; c < 8; ++c)
#pragma unroll
        for (int r = 0; r < 4; ++r) {
            float e = __expf(acc[c][r] - rowm[r]);
            acc[c][r] = e;
            rsum[r] += e;
        }
#pragma unroll
    for (int r = 0; r < 4; ++r) {
        float s = rsum[r];
        s += __shfl_xor(s, 1);
        s += __shfl_xor(s, 2);
        s += __shfl_xor(s, 4);
        s += __shfl_xor(s, 8);
        rsum[r] = s;
    }
    __syncthreads();   // red[] reuse
    if (lr == 0) {
#pragma unroll
        for (int r = 0; r < 4; ++r)
            red[wave][lk * 4 + r] = rsum[r];
    }
    __syncthreads();
    if (tid < 16) {
        float s = 0.0f;
#pragma unroll
        for (int w = 0; w < 16; ++w) s += red[w][tid];
        stat[tid] = s;
    }
    __syncthreads();

    float inv[4];
#pragma unroll
    for (int r = 0; r < 4; ++r)
        inv[r] = 1.0f / stat[lk * 4 + r];

    // ---- normalize + nontemporal store ----
#pragma unroll
    for (int c = 0; c < 8; ++c)
#pragma unroll
        for (int r = 0; r < 4; ++r) {
            int grow = row0 + lk * 4 + r;
            int col = (wave << 7) + c * 16 + lr;
            __builtin_nontemporal_store(acc[c][r] * inv[r],
                                        &out[obase + (size_t)grow * N_ + col]);
        }
}

// ---------------------------------------------------------------------------
extern "C" void kernel_launch(void* const* d_in, const int* in_sizes, int n_in,
                              void* d_out, int out_size, void* d_ws, size_t ws_size,
                              hipStream_t stream) {
    const float* x  = (const float*)d_in[0];
    const float* WQ = (const float*)d_in[1];
    const float* WK = (const float*)d_in[2];
    float* out = (float*)d_out;

    char* ws = (char*)d_ws;
    size_t off = 0;
    auto carve = [&](size_t bytes) -> char* {
        char* p = ws + off;
        off += (bytes + 255) & ~(size_t)255;
        return p;
    };
    f16*   mth = (f16*)carve((size_t)T_ * T_ * 2);
    f16*   mtl = (f16*)carve((size_t)T_ * T_ * 2);
    f16*   bpk = (f16*)carve((size_t)B_ * N_ * T_ * 2 * 2);   // 25.2 MB
    float* yw  = (float*)carve((size_t)B_ * N_ * T_ * 4);     // 12.6 MB
    (void)ws_size; (void)in_sizes; (void)n_in; (void)out_size;

    k_m<<<(T_ * T_ + 255) / 256, 256, 0, stream>>>(WQ, WK, mth, mtl);
    k_fuse<<<(B_ * N_) / 128, 256, 0, stream>>>(x, mth, mtl, yw, bpk);
    k_attn<<<B_ * (N_ / 16), 1024, 0, stream>>>(bpk, yw, out);
}

// Round 7
// 158.508 us; speedup vs baseline: 1.0783x; 1.0783x over previous
//
#include <hip/hip_runtime.h>
#include <hip/hip_bf16.h>

// Variable_Attention: out = softmax(relu((x@WQ)(x@WK)^T)/sqrt(128), axis=-1)
// B=16, N=2048, T=96, D=128. fp32 in/out.
//
// QK^T/sqrt(d) = x Ms x^T with Ms = (WQ WK^T)/sqrt(d) (96x96, exact fp32):
//   k_m    : Ms^T -> fp16 hi/lo split (mth/mtl)
//   k_fuse : reads x once (LDS-staged); emits y = x@Ms (fp32, pre-scaled)
//            and Bp = x split fp16 hi/lo in MFMA B-fragment stream order
//            Bp[gct(2048)][ks(3)][hl(2)][lane(64)][8] (1KB bursts per frag)
//   k_attn : S = y@x^T (K=96, 3-term split-fp16 MFMA) fused relu/softmax.
//            BM=32/block, 512 thr, wave owns 256 cols (16 col-tiles).
//            B loads are inline-asm global_load_dwordx4 with explicit
//            s_waitcnt vmcnt(6) + sched_barrier(0): compiler CANNOT collapse
//            the depth-2 register pipeline (round-6 failure: VGPR=56 proved
//            the intrinsic-load ping-pong was sunk to point-of-use).
// Workspace: ~38 MB.

typedef _Float16 f16;
typedef _Float16 half8 __attribute__((ext_vector_type(8)));
typedef float float4v __attribute__((ext_vector_type(4)));

#define B_ 16
#define N_ 2048
#define T_ 96
#define D_ 128

static __device__ __forceinline__ half8 as_h8(float4v v) {
    union { float4v f; half8 h; } u; u.f = v; return u.h;
}

// ---------------------------------------------------------------------------
// k_m: Ms[t][t2] = (sum_d WQ[t,d]*WK[t2,d])/sqrt(128), transposed + split.
// ---------------------------------------------------------------------------
__global__ void k_m(const float* __restrict__ WQ, const float* __restrict__ WK,
                    f16* __restrict__ mth, f16* __restrict__ mtl) {
    int i = blockIdx.x * 256 + threadIdx.x;
    if (i >= T_ * T_) return;
    int t = i / T_, t2 = i % T_;
    const float4v* q = (const float4v*)(WQ + (size_t)t * D_);
    const float4v* k = (const float4v*)(WK + (size_t)t2 * D_);
    float s = 0.0f;
#pragma unroll
    for (int d = 0; d < D_ / 4; ++d) {
        float4v a = q[d], b = k[d];
        s += a[0] * b[0] + a[1] * b[1] + a[2] * b[2] + a[3] * b[3];
    }
    s *= 0.088388347648318447f;   // 1/sqrt(128) folded in (exact fp32 here)
    f16 h = (f16)s;
    mth[t2 * T_ + t] = h;
    mtl[t2 * T_ + t] = (f16)(s - (float)h);
}

// ---------------------------------------------------------------------------
// k_fuse: per block, 128 x-rows staged in LDS (fp32, padded to 100 floats);
// (a) y = x@Ms via split-fp16 MFMA (wave owns 32 rows), (b) Bp pack
// (wave owns 2 col-tiles): frag[gct][ks][hl] = 1KB contiguous.
// ---------------------------------------------------------------------------
__global__ __launch_bounds__(256) void k_fuse(
        const float* __restrict__ x,
        const f16* __restrict__ mth, const f16* __restrict__ mtl,
        float* __restrict__ y, f16* __restrict__ bp) {
    __shared__ float xs[128][100];   // 51.2 KB, +4 pad -> conflict-free reads

    const int tid  = (int)threadIdx.x;
    const int lane = tid & 63;
    const int wave = tid >> 6;
    const int lr = lane & 15;
    const int lk = lane >> 4;
    const size_t rbase = (size_t)blockIdx.x * 128;

    // ---- fill LDS: 128 rows x 96 floats, fully coalesced float4 ----
    const float4v* xg = (const float4v*)(x + rbase * T_);
#pragma unroll
    for (int i = 0; i < 12; ++i) {
        int j = i * 256 + tid;           // 3072 float4 chunks
        int row = j / 24, c4 = j % 24;
        float4v v = xg[j];
        *(float4v*)&xs[row][c4 * 4] = v;
    }
    __syncthreads();

    // ---- y-GEMM: wave owns rows [wave*32, +32) ----
    half8 aH[2][3], aL[2][3];
#pragma unroll
    for (int mt = 0; mt < 2; ++mt)
#pragma unroll
        for (int ks = 0; ks < 3; ++ks) {
            const float* p = &xs[wave * 32 + mt * 16 + lr][ks * 32 + lk * 8];
            float4v v0 = *(const float4v*)p;
            float4v v1 = *(const float4v*)(p + 4);
            half8 h, l;
#pragma unroll
            for (int j = 0; j < 4; ++j) {
                f16 h0 = (f16)v0[j]; h[j] = h0; l[j] = (f16)(v0[j] - (float)h0);
                f16 h1 = (f16)v1[j]; h[4 + j] = h1; l[4 + j] = (f16)(v1[j] - (float)h1);
            }
            aH[mt][ks] = h;
            aL[mt][ks] = l;
        }

    float4v acc[2][6];
#pragma unroll
    for (int mt = 0; mt < 2; ++mt)
#pragma unroll
        for (int nt = 0; nt < 6; ++nt) {
            float4v z = {0.f, 0.f, 0.f, 0.f};
            acc[mt][nt] = z;
        }

#pragma unroll
    for (int nt = 0; nt < 6; ++nt) {
        half8 bH[3], bL[3];
#pragma unroll
        for (int ks = 0; ks < 3; ++ks) {
            size_t off = (size_t)(nt * 16 + lr) * T_ + ks * 32 + lk * 8;
            bH[ks] = *(const half8*)(mth + off);
            bL[ks] = *(const half8*)(mtl + off);
        }
#pragma unroll
        for (int ks = 0; ks < 3; ++ks)
#pragma unroll
            for (int mt = 0; mt < 2; ++mt) {
                acc[mt][nt] = __builtin_amdgcn_mfma_f32_16x16x32_f16(aH[mt][ks], bH[ks], acc[mt][nt], 0, 0, 0);
                acc[mt][nt] = __builtin_amdgcn_mfma_f32_16x16x32_f16(aH[mt][ks], bL[ks], acc[mt][nt], 0, 0, 0);
                acc[mt][nt] = __builtin_amdgcn_mfma_f32_16x16x32_f16(aL[mt][ks], bH[ks], acc[mt][nt], 0, 0, 0);
            }
    }

#pragma unroll
    for (int mt = 0; mt < 2; ++mt)
#pragma unroll
        for (int nt = 0; nt < 6; ++nt)
#pragma unroll
            for (int r = 0; r < 4; ++r)
                y[(rbase + wave * 32 + mt * 16 + lk * 4 + r) * T_ + nt * 16 + lr] = acc[mt][nt][r];

    // ---- Bp pack: wave owns col-tiles wave*2 + {0,1} of this block ----
#pragma unroll
    for (int ctl = 0; ctl < 2; ++ctl) {
        const int lct = wave * 2 + ctl;                 // 0..7
        const size_t gct = rbase / 16 + lct;            // global col-tile
#pragma unroll
        for (int ks = 0; ks < 3; ++ks) {
            const float* p = &xs[lct * 16 + lr][ks * 32 + lk * 8];
            float4v v0 = *(const float4v*)p;
            float4v v1 = *(const float4v*)(p + 4);
            half8 h, l;
#pragma unroll
            for (int j = 0; j < 4; ++j) {
                f16 h0 = (f16)v0[j]; h[j] = h0; l[j] = (f16)(v0[j] - (float)h0);
                f16 h1 = (f16)v1[j]; h[4 + j] = h1; l[4 + j] = (f16)(v1[j] - (float)h1);
            }
            f16* ob = bp + ((gct * 3 + ks) * 2) * 512 + (size_t)lane * 8;
            *(half8*)ob = h;
            *(half8*)(ob + 512) = l;
        }
    }
}

// ---------------------------------------------------------------------------
// k_attn: S = y @ x^T fused relu/softmax. 32 rows x 2048 cols per block,
// 512 threads (8 waves), wave owns 256 cols = 16 col-tiles.
// Asm-pipelined B: depth-2 register sets, explicit vmcnt(6), sched fences.
// ---------------------------------------------------------------------------
__global__ __launch_bounds__(512, 2) void k_attn(
        const f16* __restrict__ bp, const float* __restrict__ y,
        float* __restrict__ out) {
    __shared__ float red[8][32];
    __shared__ float stat[32];

    const int tid  = (int)threadIdx.x;
    const int lane = tid & 63;
    const int wave = tid >> 6;
    const int lr = lane & 15;
    const int lk = lane >> 4;

    // XCD-aware bijective swizzle (1024 blocks): contiguous logical range per
    // XCD -> ~2 batches' Bp (1.6MB) resident in its L2.
    const int lb   = ((int)blockIdx.x & 7) * 128 + ((int)blockIdx.x >> 3);
    const int b    = lb >> 6;
    const int row0 = (lb & 63) << 5;          // 32 rows per block
    const size_t obase = (size_t)b * N_ * N_;

    // ---- A: y rows (fp32, pre-scaled) split on the fly (read-once, NT) ----
    half8 aH[2][3], aL[2][3];
#pragma unroll
    for (int mt = 0; mt < 2; ++mt)
#pragma unroll
        for (int ks = 0; ks < 3; ++ks) {
            const float* p = y + ((size_t)b * N_ + row0 + mt * 16 + lr) * T_ + ks * 32 + lk * 8;
            float4v v0 = __builtin_nontemporal_load((const float4v*)p);
            float4v v1 = __builtin_nontemporal_load((const float4v*)p + 1);
            half8 h, l;
#pragma unroll
            for (int j = 0; j < 4; ++j) {
                f16 h0 = (f16)v0[j]; h[j] = h0; l[j] = (f16)(v0[j] - (float)h0);
                f16 h1 = (f16)v1[j]; h[4 + j] = h1; l[4 + j] = (f16)(v1[j] - (float)h1);
            }
            aH[mt][ks] = h;
            aL[mt][ks] = l;
        }

    float4v acc[2][16];
#pragma unroll
    for (int mt = 0; mt < 2; ++mt)
#pragma unroll
        for (int c = 0; c < 16; ++c) {
            float4v z = {0.f, 0.f, 0.f, 0.f};
            acc[mt][c] = z;
        }

    // per-lane global source base for this wave's 16 col-tiles
    const f16* gb = bp + (((size_t)b * 128 + wave * 16) * 6) * 512 + (size_t)lane * 8;

    // Two depth-2 register sets, filled ONLY by asm volatile loads.
    float4v b0[6], b1[6];

#define ISSUE(ct, dst)                                                        \
    {                                                                         \
        _Pragma("unroll")                                                     \
        for (int f = 0; f < 6; ++f) {                                         \
            const f16* g = gb + (size_t)(ct) * 3072 + f * 512;                \
            asm volatile("global_load_dwordx4 %0, %1, off"                    \
                         : "=&v"(dst[f]) : "v"(g));                           \
        }                                                                     \
    }

    ISSUE(0, b0);
    ISSUE(1, b1);
    __builtin_amdgcn_sched_barrier(0);

#pragma unroll
    for (int c = 0; c < 16; ++c) {
        if (c < 15) asm volatile("s_waitcnt vmcnt(6)" ::: "memory");
        else        asm volatile("s_waitcnt vmcnt(0)" ::: "memory");
        __builtin_amdgcn_sched_barrier(0);

        __builtin_amdgcn_s_setprio(1);
        if ((c & 1) == 0) {
#pragma unroll
            for (int ks = 0; ks < 3; ++ks) {
                acc[0][c] = __builtin_amdgcn_mfma_f32_16x16x32_f16(aH[0][ks], as_h8(b0[ks * 2]),     acc[0][c], 0, 0, 0);
                acc[1][c] = __builtin_amdgcn_mfma_f32_16x16x32_f16(aH[1][ks], as_h8(b0[ks * 2]),     acc[1][c], 0, 0, 0);
                acc[0][c] = __builtin_amdgcn_mfma_f32_16x16x32_f16(aH[0][ks], as_h8(b0[ks * 2 + 1]), acc[0][c], 0, 0, 0);
                acc[1][c] = __builtin_amdgcn_mfma_f32_16x16x32_f16(aH[1][ks], as_h8(b0[ks * 2 + 1]), acc[1][c], 0, 0, 0);
                acc[0][c] = __builtin_amdgcn_mfma_f32_16x16x32_f16(aL[0][ks], as_h8(b0[ks * 2]),     acc[0][c], 0, 0, 0);
                acc[1][c] = __builtin_amdgcn_mfma_f32_16x16x32_f16(aL[1][ks], as_h8(b0[ks * 2]),     acc[1][c], 0, 0, 0);
            }
            __builtin_amdgcn_s_setprio(0);
            __builtin_amdgcn_sched_barrier(0);
            if (c + 2 < 16) ISSUE(c + 2, b0);
        } else {
#pragma unroll
            for (int ks = 0; ks < 3; ++ks) {
                acc[0][c] = __builtin_amdgcn_mfma_f32_16x16x32_f16(aH[0][ks], as_h8(b1[ks * 2]),     acc[0][c], 0, 0, 0);
                acc[1][c] = __builtin_amdgcn_mfma_f32_16x16x32_f16(aH[1][ks], as_h8(b1[ks * 2]),     acc[1][c], 0, 0, 0);
                acc[0][c] = __builtin_amdgcn_mfma_f32_16x16x32_f16(aH[0][ks], as_h8(b1[ks * 2 + 1]), acc[0][c], 0, 0, 0);
                acc[1][c] = __builtin_amdgcn_mfma_f32_16x16x32_f16(aH[1][ks], as_h8(b1[ks * 2 + 1]), acc[1][c], 0, 0, 0);
                acc[0][c] = __builtin_amdgcn_mfma_f32_16x16x32_f16(aL[0][ks], as_h8(b1[ks * 2]),     acc[0][c], 0, 0, 0);
                acc[1][c] = __builtin_amdgcn_mfma_f32_16x16x32_f16(aL[1][ks], as_h8(b1[ks * 2]),     acc[1][c], 0, 0, 0);
            }
            __builtin_amdgcn_s_setprio(0);
            __builtin_amdgcn_sched_barrier(0);
            if (c + 2 < 16) ISSUE(c + 2, b1);
        }
        __builtin_amdgcn_sched_barrier(0);
    }
#undef ISSUE

    // ---- relu (scale folded into Ms), row max ----
    float rmax[2][4];
#pragma unroll
    for (int mt = 0; mt < 2; ++mt)
#pragma unroll
        for (int r = 0; r < 4; ++r) rmax[mt][r] = 0.0f;
#pragma unroll
    for (int mt = 0; mt < 2; ++mt)
#pragma unroll
        for (int c = 0; c < 16; ++c)
#pragma unroll
            for (int r = 0; r < 4; ++r) {
                float v = fmaxf(acc[mt][c][r], 0.0f);
                acc[mt][c][r] = v;
                rmax[mt][r] = fmaxf(rmax[mt][r], v);
            }
#pragma unroll
    for (int mt = 0; mt < 2; ++mt)
#pragma unroll
        for (int r = 0; r < 4; ++r) {
            float m = rmax[mt][r];
            m = fmaxf(m, __shfl_xor(m, 1));
            m = fmaxf(m, __shfl_xor(m, 2));
            m = fmaxf(m, __shfl_xor(m, 4));
            m = fmaxf(m, __shfl_xor(m, 8));
            rmax[mt][r] = m;
        }
    if (lr == 0) {
#pragma unroll
        for (int mt = 0; mt < 2; ++mt)
#pragma unroll
            for (int r = 0; r < 4; ++r)
                red[wave][mt * 16 + lk * 4 + r] = rmax[mt][r];
    }
    __syncthreads();
    if (tid < 32) {
        float m = red[0][tid];
#pragma unroll
        for (int w = 1; w < 8; ++w) m = fmaxf(m, red[w][tid]);
        stat[tid] = m;
    }
    __syncthreads();

    float rowm[2][4], rsum[2][4];
#pragma unroll
    for (int mt = 0; mt < 2; ++mt)
#pragma unroll
        for (int r = 0; r < 4; ++r) {
            rowm[mt][r] = stat[mt * 16 + lk * 4 + r];
            rsum[mt][r] = 0.0f;
        }

    // ---- exp, row sum ----
#pragma unroll
    for (int mt = 0; mt < 2; ++mt)
#pragma unroll
        for (int c = 0; c < 16; ++c)
#pragma unroll
            for (int r = 0; r < 4; ++r) {
                float e = __expf(acc[mt][c][r] - rowm[mt][r]);
                acc[mt][c][r] = e;
                rsum[mt][r] += e;
            }
#pragma unroll
    for (int mt = 0; mt < 2; ++mt)
#pragma unroll
        for (int r = 0; r < 4; ++r) {
            float s = rsum[mt][r];
            s += __shfl_xor(s, 1);
            s += __shfl_xor(s, 2);
            s += __shfl_xor(s, 4);
            s += __shfl_xor(s, 8);
            rsum[mt][r] = s;
        }
    __syncthreads();
    if (lr == 0) {
#pragma unroll
        for (int mt = 0; mt < 2; ++mt)
#pragma unroll
            for (int r = 0; r < 4; ++r)
                red[wave][mt * 16 + lk * 4 + r] = rsum[mt][r];
    }
    __syncthreads();
    if (tid < 32) {
        float s = 0.0f;
#pragma unroll
        for (int w = 0; w < 8; ++w) s += red[w][tid];
        stat[tid] = s;
    }
    __syncthreads();

    float inv[2][4];
#pragma unroll
    for (int mt = 0; mt < 2; ++mt)
#pragma unroll
        for (int r = 0; r < 4; ++r)
            inv[mt][r] = 1.0f / stat[mt * 16 + lk * 4 + r];

    // ---- normalize + nontemporal store ----
#pragma unroll
    for (int mt = 0; mt < 2; ++mt)
#pragma unroll
        for (int c = 0; c < 16; ++c)
#pragma unroll
            for (int r = 0; r < 4; ++r) {
                int grow = row0 + mt * 16 + lk * 4 + r;
                int col = (wave << 8) + c * 16 + lr;
                __builtin_nontemporal_store(acc[mt][c][r] * inv[mt][r],
                                            &out[obase + (size_t)grow * N_ + col]);
            }
}

// ---------------------------------------------------------------------------
extern "C" void kernel_launch(void* const* d_in, const int* in_sizes, int n_in,
                              void* d_out, int out_size, void* d_ws, size_t ws_size,
                              hipStream_t stream) {
    const float* x  = (const float*)d_in[0];
    const float* WQ = (const float*)d_in[1];
    const float* WK = (const float*)d_in[2];
    float* out = (float*)d_out;

    char* ws = (char*)d_ws;
    size_t off = 0;
    auto carve = [&](size_t bytes) -> char* {
        char* p = ws + off;
        off += (bytes + 255) & ~(size_t)255;
        return p;
    };
    f16*   mth = (f16*)carve((size_t)T_ * T_ * 2);
    f16*   mtl = (f16*)carve((size_t)T_ * T_ * 2);
    f16*   bpk = (f16*)carve((size_t)B_ * N_ * T_ * 2 * 2);   // 25.2 MB
    float* yw  = (float*)carve((size_t)B_ * N_ * T_ * 4);     // 12.6 MB
    (void)ws_size; (void)in_sizes; (void)n_in; (void)out_size;

    k_m<<<(T_ * T_ + 255) / 256, 256, 0, stream>>>(WQ, WK, mth, mtl);
    k_fuse<<<(B_ * N_) / 128, 256, 0, stream>>>(x, mth, mtl, yw, bpk);
    k_attn<<<B_ * (N_ / 32), 512, 0, stream>>>(bpk, yw, out);
}

// Round 8
// 126.213 us; speedup vs baseline: 1.3542x; 1.2559x over previous
//
#include <hip/hip_runtime.h>
#include <hip/hip_bf16.h>

// Variable_Attention: out = softmax(relu((x@WQ)(x@WK)^T)/sqrt(128), axis=-1)
// B=16, N=2048, T=96, D=128. fp32 in/out.
//
// QK^T/sqrt(d) = x Ms x^T with Ms = (WQ WK^T)/sqrt(d) (96x96, exact fp32):
//   k_m    : Ms^T -> fp16 hi/lo split
//   k_fuse : reads x once (LDS-staged); emits y = x@Ms (fp32) and Bp = x
//            split fp16 hi/lo in MFMA B-fragment stream order (1KB frags)
//   k_attn : S = y@x^T (K=96, 3-term split-fp16 MFMA) fused relu/softmax.
//            BM=32/block, 512 thr. Asm-pipelined B loads (depth-2, vmcnt(6)).
//            KEY CHANGE (R8): output written via LDS transpose as row-
//            contiguous 1KB dwordx4 bursts. All previous rounds were bound
//            by scattered 4B/lane stores (1.4-1.7 TB/s effective write BW;
//            R3 showed 2x write amplification 545MB/262MB).
// Workspace: ~38 MB.

typedef _Float16 f16;
typedef _Float16 half8 __attribute__((ext_vector_type(8)));
typedef float float4v __attribute__((ext_vector_type(4)));

#define B_ 16
#define N_ 2048
#define T_ 96
#define D_ 128

static __device__ __forceinline__ half8 as_h8(float4v v) {
    union { float4v f; half8 h; } u; u.f = v; return u.h;
}

// ---------------------------------------------------------------------------
// k_m: Ms[t][t2] = (sum_d WQ[t,d]*WK[t2,d])/sqrt(128), transposed + split.
// ---------------------------------------------------------------------------
__global__ void k_m(const float* __restrict__ WQ, const float* __restrict__ WK,
                    f16* __restrict__ mth, f16* __restrict__ mtl) {
    int i = blockIdx.x * 256 + threadIdx.x;
    if (i >= T_ * T_) return;
    int t = i / T_, t2 = i % T_;
    const float4v* q = (const float4v*)(WQ + (size_t)t * D_);
    const float4v* k = (const float4v*)(WK + (size_t)t2 * D_);
    float s = 0.0f;
#pragma unroll
    for (int d = 0; d < D_ / 4; ++d) {
        float4v a = q[d], b = k[d];
        s += a[0] * b[0] + a[1] * b[1] + a[2] * b[2] + a[3] * b[3];
    }
    s *= 0.088388347648318447f;   // 1/sqrt(128) folded in (exact fp32 here)
    f16 h = (f16)s;
    mth[t2 * T_ + t] = h;
    mtl[t2 * T_ + t] = (f16)(s - (float)h);
}

// ---------------------------------------------------------------------------
// k_fuse: per block, 128 x-rows staged in LDS; (a) y = x@Ms (wave owns 32
// rows), (b) Bp pack (wave owns 2 col-tiles): frag[gct][ks][hl] = 1KB.
// ---------------------------------------------------------------------------
__global__ __launch_bounds__(256) void k_fuse(
        const float* __restrict__ x,
        const f16* __restrict__ mth, const f16* __restrict__ mtl,
        float* __restrict__ y, f16* __restrict__ bp) {
    __shared__ float xs[128][100];   // 51.2 KB, +4 pad -> conflict-free reads

    const int tid  = (int)threadIdx.x;
    const int lane = tid & 63;
    const int wave = tid >> 6;
    const int lr = lane & 15;
    const int lk = lane >> 4;
    const size_t rbase = (size_t)blockIdx.x * 128;

    // ---- fill LDS: 128 rows x 96 floats, fully coalesced float4 ----
    const float4v* xg = (const float4v*)(x + rbase * T_);
#pragma unroll
    for (int i = 0; i < 12; ++i) {
        int j = i * 256 + tid;           // 3072 float4 chunks
        int row = j / 24, c4 = j % 24;
        float4v v = xg[j];
        *(float4v*)&xs[row][c4 * 4] = v;
    }
    __syncthreads();

    // ---- y-GEMM: wave owns rows [wave*32, +32) ----
    half8 aH[2][3], aL[2][3];
#pragma unroll
    for (int mt = 0; mt < 2; ++mt)
#pragma unroll
        for (int ks = 0; ks < 3; ++ks) {
            const float* p = &xs[wave * 32 + mt * 16 + lr][ks * 32 + lk * 8];
            float4v v0 = *(const float4v*)p;
            float4v v1 = *(const float4v*)(p + 4);
            half8 h, l;
#pragma unroll
            for (int j = 0; j < 4; ++j) {
                f16 h0 = (f16)v0[j]; h[j] = h0; l[j] = (f16)(v0[j] - (float)h0);
                f16 h1 = (f16)v1[j]; h[4 + j] = h1; l[4 + j] = (f16)(v1[j] - (float)h1);
            }
            aH[mt][ks] = h;
            aL[mt][ks] = l;
        }

    float4v acc[2][6];
#pragma unroll
    for (int mt = 0; mt < 2; ++mt)
#pragma unroll
        for (int nt = 0; nt < 6; ++nt) {
            float4v z = {0.f, 0.f, 0.f, 0.f};
            acc[mt][nt] = z;
        }

#pragma unroll
    for (int nt = 0; nt < 6; ++nt) {
        half8 bH[3], bL[3];
#pragma unroll
        for (int ks = 0; ks < 3; ++ks) {
            size_t off = (size_t)(nt * 16 + lr) * T_ + ks * 32 + lk * 8;
            bH[ks] = *(const half8*)(mth + off);
            bL[ks] = *(const half8*)(mtl + off);
        }
#pragma unroll
        for (int ks = 0; ks < 3; ++ks)
#pragma unroll
            for (int mt = 0; mt < 2; ++mt) {
                acc[mt][nt] = __builtin_amdgcn_mfma_f32_16x16x32_f16(aH[mt][ks], bH[ks], acc[mt][nt], 0, 0, 0);
                acc[mt][nt] = __builtin_amdgcn_mfma_f32_16x16x32_f16(aH[mt][ks], bL[ks], acc[mt][nt], 0, 0, 0);
                acc[mt][nt] = __builtin_amdgcn_mfma_f32_16x16x32_f16(aL[mt][ks], bH[ks], acc[mt][nt], 0, 0, 0);
            }
    }

#pragma unroll
    for (int mt = 0; mt < 2; ++mt)
#pragma unroll
        for (int nt = 0; nt < 6; ++nt)
#pragma unroll
            for (int r = 0; r < 4; ++r)
                y[(rbase + wave * 32 + mt * 16 + lk * 4 + r) * T_ + nt * 16 + lr] = acc[mt][nt][r];

    // ---- Bp pack: wave owns col-tiles wave*2 + {0,1} of this block ----
#pragma unroll
    for (int ctl = 0; ctl < 2; ++ctl) {
        const int lct = wave * 2 + ctl;                 // 0..7
        const size_t gct = rbase / 16 + lct;            // global col-tile
#pragma unroll
        for (int ks = 0; ks < 3; ++ks) {
            const float* p = &xs[lct * 16 + lr][ks * 32 + lk * 8];
            float4v v0 = *(const float4v*)p;
            float4v v1 = *(const float4v*)(p + 4);
            half8 h, l;
#pragma unroll
            for (int j = 0; j < 4; ++j) {
                f16 h0 = (f16)v0[j]; h[j] = h0; l[j] = (f16)(v0[j] - (float)h0);
                f16 h1 = (f16)v1[j]; h[4 + j] = h1; l[4 + j] = (f16)(v1[j] - (float)h1);
            }
            f16* ob = bp + ((gct * 3 + ks) * 2) * 512 + (size_t)lane * 8;
            *(half8*)ob = h;
            *(half8*)(ob + 512) = l;
        }
    }
}

// ---------------------------------------------------------------------------
// k_attn: S = y @ x^T fused relu/softmax. 32 rows x 2048 cols per block.
// Wave w owns cols [w*128,+128) of group0 (cols 0-1023) and [1024+w*128,+128)
// of group1. Epilogue: per group, LDS transpose (32x1032 pad) then each wave
// writes 4 FULL rows as sequential 1KB dwordx4 bursts.
// ---------------------------------------------------------------------------
__global__ __launch_bounds__(512, 2) void k_attn(
        const f16* __restrict__ bp, const float* __restrict__ y,
        float* __restrict__ out) {
    __shared__ float ot[32][1032];    // 132 KB transpose buffer
    __shared__ float red[8][32];
    __shared__ float stat[32];

    const int tid  = (int)threadIdx.x;
    const int lane = tid & 63;
    const int wave = tid >> 6;
    const int lr = lane & 15;
    const int lk = lane >> 4;

    // XCD-aware bijective swizzle (1024 blocks)
    const int lb   = ((int)blockIdx.x & 7) * 128 + ((int)blockIdx.x >> 3);
    const int b    = lb >> 6;
    const int row0 = (lb & 63) << 5;          // 32 rows per block
    const size_t obase = (size_t)b * N_ * N_;

    // ---- A: y rows (fp32, pre-scaled) split on the fly (read-once, NT) ----
    half8 aH[2][3], aL[2][3];
#pragma unroll
    for (int mt = 0; mt < 2; ++mt)
#pragma unroll
        for (int ks = 0; ks < 3; ++ks) {
            const float* p = y + ((size_t)b * N_ + row0 + mt * 16 + lr) * T_ + ks * 32 + lk * 8;
            float4v v0 = __builtin_nontemporal_load((const float4v*)p);
            float4v v1 = __builtin_nontemporal_load((const float4v*)p + 1);
            half8 h, l;
#pragma unroll
            for (int j = 0; j < 4; ++j) {
                f16 h0 = (f16)v0[j]; h[j] = h0; l[j] = (f16)(v0[j] - (float)h0);
                f16 h1 = (f16)v1[j]; h[4 + j] = h1; l[4 + j] = (f16)(v1[j] - (float)h1);
            }
            aH[mt][ks] = h;
            aL[mt][ks] = l;
        }

    float4v acc[2][16];
#pragma unroll
    for (int mt = 0; mt < 2; ++mt)
#pragma unroll
        for (int c = 0; c < 16; ++c) {
            float4v z = {0.f, 0.f, 0.f, 0.f};
            acc[mt][c] = z;
        }

    // col-tile index for loop index c (group-contiguous mapping):
    //   c<8 : tile = wave*8 + c         (cols wave*128 + c*16 in [0,1024))
    //   c>=8: tile = 64 + wave*8 + c-8  (cols 1024 + wave*128 + (c-8)*16)
#define TIDX(c) (((c) & 8 ? 64 : 0) + (wave << 3) + ((c) & 7))

    const f16* gb = bp + ((size_t)b * 128 * 6) * 512 + (size_t)lane * 8;

    float4v b0[6], b1[6];
#define ISSUE(ti, dst)                                                        \
    {                                                                         \
        _Pragma("unroll")                                                     \
        for (int f = 0; f < 6; ++f) {                                         \
            const f16* g = gb + (size_t)(ti) * 3072 + f * 512;                \
            asm volatile("global_load_dwordx4 %0, %1, off"                    \
                         : "=&v"(dst[f]) : "v"(g));                           \
        }                                                                     \
    }

    ISSUE(TIDX(0), b0);
    ISSUE(TIDX(1), b1);
    __builtin_amdgcn_sched_barrier(0);

#pragma unroll
    for (int c = 0; c < 16; ++c) {
        if (c < 15) asm volatile("s_waitcnt vmcnt(6)" ::: "memory");
        else        asm volatile("s_waitcnt vmcnt(0)" ::: "memory");
        __builtin_amdgcn_sched_barrier(0);

        __builtin_amdgcn_s_setprio(1);
        if ((c & 1) == 0) {
#pragma unroll
            for (int ks = 0; ks < 3; ++ks) {
                acc[0][c] = __builtin_amdgcn_mfma_f32_16x16x32_f16(aH[0][ks], as_h8(b0[ks * 2]),     acc[0][c], 0, 0, 0);
                acc[1][c] = __builtin_amdgcn_mfma_f32_16x16x32_f16(aH[1][ks], as_h8(b0[ks * 2]),     acc[1][c], 0, 0, 0);
                acc[0][c] = __builtin_amdgcn_mfma_f32_16x16x32_f16(aH[0][ks], as_h8(b0[ks * 2 + 1]), acc[0][c], 0, 0, 0);
                acc[1][c] = __builtin_amdgcn_mfma_f32_16x16x32_f16(aH[1][ks], as_h8(b0[ks * 2 + 1]), acc[1][c], 0, 0, 0);
                acc[0][c] = __builtin_amdgcn_mfma_f32_16x16x32_f16(aL[0][ks], as_h8(b0[ks * 2]),     acc[0][c], 0, 0, 0);
                acc[1][c] = __builtin_amdgcn_mfma_f32_16x16x32_f16(aL[1][ks], as_h8(b0[ks * 2]),     acc[1][c], 0, 0, 0);
            }
            __builtin_amdgcn_s_setprio(0);
            __builtin_amdgcn_sched_barrier(0);
            if (c + 2 < 16) ISSUE(TIDX(c + 2), b0);
        } else {
#pragma unroll
            for (int ks = 0; ks < 3; ++ks) {
                acc[0][c] = __builtin_amdgcn_mfma_f32_16x16x32_f16(aH[0][ks], as_h8(b1[ks * 2]),     acc[0][c], 0, 0, 0);
                acc[1][c] = __builtin_amdgcn_mfma_f32_16x16x32_f16(aH[1][ks], as_h8(b1[ks * 2]),     acc[1][c], 0, 0, 0);
                acc[0][c] = __builtin_amdgcn_mfma_f32_16x16x32_f16(aH[0][ks], as_h8(b1[ks * 2 + 1]), acc[0][c], 0, 0, 0);
                acc[1][c] = __builtin_amdgcn_mfma_f32_16x16x32_f16(aH[1][ks], as_h8(b1[ks * 2 + 1]), acc[1][c], 0, 0, 0);
                acc[0][c] = __builtin_amdgcn_mfma_f32_16x16x32_f16(aL[0][ks], as_h8(b1[ks * 2]),     acc[0][c], 0, 0, 0);
                acc[1][c] = __builtin_amdgcn_mfma_f32_16x16x32_f16(aL[1][ks], as_h8(b1[ks * 2]),     acc[1][c], 0, 0, 0);
            }
            __builtin_amdgcn_s_setprio(0);
            __builtin_amdgcn_sched_barrier(0);
            if (c + 2 < 16) ISSUE(TIDX(c + 2), b1);
        }
        __builtin_amdgcn_sched_barrier(0);
    }
#undef ISSUE
#undef TIDX

    // ---- relu (scale folded into Ms), row max ----
    float rmax[2][4];
#pragma unroll
    for (int mt = 0; mt < 2; ++mt)
#pragma unroll
        for (int r = 0; r < 4; ++r) rmax[mt][r] = 0.0f;
#pragma unroll
    for (int mt = 0; mt < 2; ++mt)
#pragma unroll
        for (int c = 0; c < 16; ++c)
#pragma unroll
            for (int r = 0; r < 4; ++r) {
                float v = fmaxf(acc[mt][c][r], 0.0f);
                acc[mt][c][r] = v;
                rmax[mt][r] = fmaxf(rmax[mt][r], v);
            }
#pragma unroll
    for (int mt = 0; mt < 2; ++mt)
#pragma unroll
        for (int r = 0; r < 4; ++r) {
            float m = rmax[mt][r];
            m = fmaxf(m, __shfl_xor(m, 1));
            m = fmaxf(m, __shfl_xor(m, 2));
            m = fmaxf(m, __shfl_xor(m, 4));
            m = fmaxf(m, __shfl_xor(m, 8));
            rmax[mt][r] = m;
        }
    if (lr == 0) {
#pragma unroll
        for (int mt = 0; mt < 2; ++mt)
#pragma unroll
            for (int r = 0; r < 4; ++r)
                red[wave][mt * 16 + lk * 4 + r] = rmax[mt][r];
    }
    __syncthreads();
    if (tid < 32) {
        float m = red[0][tid];
#pragma unroll
        for (int w = 1; w < 8; ++w) m = fmaxf(m, red[w][tid]);
        stat[tid] = m;
    }
    __syncthreads();

    float rowm[2][4], rsum[2][4];
#pragma unroll
    for (int mt = 0; mt < 2; ++mt)
#pragma unroll
        for (int r = 0; r < 4; ++r) {
            rowm[mt][r] = stat[mt * 16 + lk * 4 + r];
            rsum[mt][r] = 0.0f;
        }

    // ---- exp, row sum ----
#pragma unroll
    for (int mt = 0; mt < 2; ++mt)
#pragma unroll
        for (int c = 0; c < 16; ++c)
#pragma unroll
            for (int r = 0; r < 4; ++r) {
                float e = __expf(acc[mt][c][r] - rowm[mt][r]);
                acc[mt][c][r] = e;
                rsum[mt][r] += e;
            }
#pragma unroll
    for (int mt = 0; mt < 2; ++mt)
#pragma unroll
        for (int r = 0; r < 4; ++r) {
            float s = rsum[mt][r];
            s += __shfl_xor(s, 1);
            s += __shfl_xor(s, 2);
            s += __shfl_xor(s, 4);
            s += __shfl_xor(s, 8);
            rsum[mt][r] = s;
        }
    __syncthreads();
    if (lr == 0) {
#pragma unroll
        for (int mt = 0; mt < 2; ++mt)
#pragma unroll
            for (int r = 0; r < 4; ++r)
                red[wave][mt * 16 + lk * 4 + r] = rsum[mt][r];
    }
    __syncthreads();
    if (tid < 32) {
        float s = 0.0f;
#pragma unroll
        for (int w = 0; w < 8; ++w) s += red[w][tid];
        stat[tid] = s;
    }
    __syncthreads();

    float inv[2][4];
#pragma unroll
    for (int mt = 0; mt < 2; ++mt)
#pragma unroll
        for (int r = 0; r < 4; ++r)
            inv[mt][r] = 1.0f / stat[mt * 16 + lk * 4 + r];

    // ---- normalize + LDS transpose + row-contiguous burst stores ----
#pragma unroll
    for (int g = 0; g < 2; ++g) {
        if (g) __syncthreads();   // protect ot reuse
#pragma unroll
        for (int cc = 0; cc < 8; ++cc) {
            const int c = g * 8 + cc;
#pragma unroll
            for (int mt = 0; mt < 2; ++mt)
#pragma unroll
                for (int r = 0; r < 4; ++r)
                    ot[mt * 16 + lk * 4 + r][(wave << 7) + cc * 16 + lr] =
                        acc[mt][c][r] * inv[mt][r];
        }
        __syncthreads();
        // each wave writes 4 full rows of this 1024-col group: 1KB bursts
#pragma unroll
        for (int rr = 0; rr < 4; ++rr) {
            const int row = (wave << 2) + rr;
            float* dstp = out + obase + (size_t)(row0 + row) * N_ + g * 1024;
#pragma unroll
            for (int i = 0; i < 4; ++i) {
                float4v v = *(const float4v*)&ot[row][i * 256 + lane * 4];
                *(float4v*)(dstp + i * 256 + lane * 4) = v;
            }
        }
    }
}

// ---------------------------------------------------------------------------
extern "C" void kernel_launch(void* const* d_in, const int* in_sizes, int n_in,
                              void* d_out, int out_size, void* d_ws, size_t ws_size,
                              hipStream_t stream) {
    const float* x  = (const float*)d_in[0];
    const float* WQ = (const float*)d_in[1];
    const float* WK = (const float*)d_in[2];
    float* out = (float*)d_out;

    char* ws = (char*)d_ws;
    size_t off = 0;
    auto carve = [&](size_t bytes) -> char* {
        char* p = ws + off;
        off += (bytes + 255) & ~(size_t)255;
        return p;
    };
    f16*   mth = (f16*)carve((size_t)T_ * T_ * 2);
    f16*   mtl = (f16*)carve((size_t)T_ * T_ * 2);
    f16*   bpk = (f16*)carve((size_t)B_ * N_ * T_ * 2 * 2);   // 25.2 MB
    float* yw  = (float*)carve((size_t)B_ * N_ * T_ * 4);     // 12.6 MB
    (void)ws_size; (void)in_sizes; (void)n_in; (void)out_size;

    k_m<<<(T_ * T_ + 255) / 256, 256, 0, stream>>>(WQ, WK, mth, mtl);
    k_fuse<<<(B_ * N_) / 128, 256, 0, stream>>>(x, mth, mtl, yw, bpk);
    k_attn<<<B_ * (N_ / 32), 512, 0, stream>>>(bpk, yw, out);
}